// Round 1
// baseline (1755.251 us; speedup 1.0000x reference)
//
#include <hip/hip_runtime.h>
#include <stdint.h>

// MixtureOfSoftmaxes: B=1024, H=4, D=256, V=100000
// out[b,v] = sum_h pi[b,h] * softmax_v(proj[b,h,:]·emb[v,:])
// Scheme: no-max softmax (logits bounded ~|l|<3):
//   pass C: s[m] = sum_v exp(l[m,v])   (m = b*4+h)
//   pass D: out[b,v] = sum_h (pi/s)[m] * exp(l[m,v])

#define VOCAB 100000

typedef __attribute__((ext_vector_type(8))) short short8;
typedef __attribute__((ext_vector_type(4))) float f32x4;

__device__ __forceinline__ short f2bf(float f) {
  uint32_t u = __float_as_uint(f);
  u = (u + 0x7FFFu + ((u >> 16) & 1u)) >> 16;
  return (short)u;
}

// ---------------- kernel 1: proj = tanh(x @ proj_mat^T) -> bf16 [1024 x 1024] ----
__global__ __launch_bounds__(256) void proj_kernel(const float* __restrict__ x,
                                                   const float* __restrict__ pm,
                                                   short* __restrict__ projA) {
  __shared__ float xs[64][36];
  __shared__ float ps[64][36];
  const int tid = threadIdx.x;
  const int tx = tid & 15, ty = tid >> 4;
  const int m0 = blockIdx.y * 64, n0 = blockIdx.x * 64;
  float acc[4][4];
#pragma unroll
  for (int i = 0; i < 4; i++)
#pragma unroll
    for (int j = 0; j < 4; j++) acc[i][j] = 0.f;

  for (int k0 = 0; k0 < 256; k0 += 32) {
    const int r = tid >> 2, c = (tid & 3) * 8;
    *(float4*)&xs[r][c]     = *(const float4*)&x[(m0 + r) * 256 + k0 + c];
    *(float4*)&xs[r][c + 4] = *(const float4*)&x[(m0 + r) * 256 + k0 + c + 4];
    *(float4*)&ps[r][c]     = *(const float4*)&pm[(n0 + r) * 256 + k0 + c];
    *(float4*)&ps[r][c + 4] = *(const float4*)&pm[(n0 + r) * 256 + k0 + c + 4];
    __syncthreads();
#pragma unroll
    for (int kk = 0; kk < 32; kk += 4) {
      float4 xa[4], pb[4];
#pragma unroll
      for (int i = 0; i < 4; i++) xa[i] = *(const float4*)&xs[ty * 4 + i][kk];
#pragma unroll
      for (int j = 0; j < 4; j++) pb[j] = *(const float4*)&ps[tx * 4 + j][kk];
#pragma unroll
      for (int i = 0; i < 4; i++)
#pragma unroll
        for (int j = 0; j < 4; j++)
          acc[i][j] += xa[i].x * pb[j].x + xa[i].y * pb[j].y +
                       xa[i].z * pb[j].z + xa[i].w * pb[j].w;
    }
    __syncthreads();
  }
#pragma unroll
  for (int i = 0; i < 4; i++)
#pragma unroll
    for (int j = 0; j < 4; j++)
      projA[(size_t)(m0 + ty * 4 + i) * 1024 + (n0 + tx * 4 + j)] = f2bf(tanhf(acc[i][j]));
}

// ---------------- kernel 2: pi = softmax(x @ mix_mat^T)  [1024 x 4] --------------
__global__ __launch_bounds__(256) void pi_kernel(const float* __restrict__ x,
                                                 const float* __restrict__ mm,
                                                 float* __restrict__ pi) {
  int b = blockIdx.x * 256 + threadIdx.x;
  if (b >= 1024) return;
  float acc[4] = {0.f, 0.f, 0.f, 0.f};
  for (int k = 0; k < 256; k += 4) {
    float4 xv = *(const float4*)&x[(size_t)b * 256 + k];
#pragma unroll
    for (int h = 0; h < 4; h++) {
      float4 mv = *(const float4*)&mm[h * 256 + k];
      acc[h] += xv.x * mv.x + xv.y * mv.y + xv.z * mv.z + xv.w * mv.w;
    }
  }
  float mx = fmaxf(fmaxf(acc[0], acc[1]), fmaxf(acc[2], acc[3]));
  float e[4], ssum = 0.f;
#pragma unroll
  for (int h = 0; h < 4; h++) { e[h] = __expf(acc[h] - mx); ssum += e[h]; }
#pragma unroll
  for (int h = 0; h < 4; h++) pi[b * 4 + h] = e[h] / ssum;
}

// ---------------- kernel 3/5: big GEMM + epilogue --------------------------------
// MODE 0: accumulate s[m] = sum_v exp(l)  (atomicAdd)
// MODE 1: out[b,v] = sum_h w[m]*exp(l),  w = pi/s
template <int MODE>
__global__ __launch_bounds__(256) void mos_gemm(const float* __restrict__ emb,
                                                const short* __restrict__ projA,
                                                const float* __restrict__ w,
                                                float* __restrict__ s,
                                                float* __restrict__ out) {
  __shared__ short embT[128 * 256];   // 64 KB, bf16, swizzled
  __shared__ short projT[128 * 256];  // 64 KB, bf16, swizzled
  const int tid = threadIdx.x;
  const int lane = tid & 63, wid = tid >> 6;
  const int wr = wid >> 1, wc = wid & 1;
  const int lr = lane & 15, lk = lane >> 4;
  const int v0 = blockIdx.x * 128;

  // ---- stage emb tile once: fp32 -> bf16, chunk^(row&7) swizzle ----
  for (int it = 0; it < 16; ++it) {
    int chunk = it * 256 + tid;         // 0..4095 (16B chunks)
    int r = chunk >> 5, c = chunk & 31; // row (v), chunk col
    int v = v0 + r;
    float4 f0 = {0.f, 0.f, 0.f, 0.f}, f1 = {0.f, 0.f, 0.f, 0.f};
    if (v < VOCAB) {
      f0 = *(const float4*)&emb[(size_t)v * 256 + c * 8];
      f1 = *(const float4*)&emb[(size_t)v * 256 + c * 8 + 4];
    }
    short8 b8;
    b8[0] = f2bf(f0.x); b8[1] = f2bf(f0.y); b8[2] = f2bf(f0.z); b8[3] = f2bf(f0.w);
    b8[4] = f2bf(f1.x); b8[5] = f2bf(f1.y); b8[6] = f2bf(f1.z); b8[7] = f2bf(f1.w);
    *(short8*)&embT[r * 256 + ((c ^ (r & 7)) << 3)] = b8;
  }

  for (int mt = 0; mt < 32; ++mt) {
    __syncthreads();  // prev reads done (and emb writes on mt=0) before restage
    // ---- stage projT via global_load_lds, pre-swizzled global source ----
#pragma unroll
    for (int j = 0; j < 16; ++j) {
      int g = j * 256 + tid;            // linear 16B chunk in LDS
      int r = g >> 5, c = g & 31;
      const char* src = (const char*)projA +
                        ((size_t)(mt * 128 + r) * 512 + ((c ^ (r & 7)) << 4));
      char* dst = (char*)projT + (j * 4096 + wid * 1024);  // wave-uniform base
      __builtin_amdgcn_global_load_lds((const __attribute__((address_space(1))) void*)src,
                                       (__attribute__((address_space(3))) void*)dst,
                                       16, 0, 0);
    }
    __syncthreads();  // compiler drains vmcnt before barrier -> projT ready

    f32x4 acc[4][4];
#pragma unroll
    for (int mi = 0; mi < 4; mi++)
#pragma unroll
      for (int ni = 0; ni < 4; ni++) acc[mi][ni] = (f32x4){0.f, 0.f, 0.f, 0.f};

#pragma unroll
    for (int ks = 0; ks < 8; ++ks) {
      short8 a[4], b[4];
#pragma unroll
      for (int mi = 0; mi < 4; ++mi) {
        int row = wr * 64 + mi * 16 + lr;
        a[mi] = *(const short8*)&projT[row * 256 + (((ks * 4 + lk) ^ (row & 7)) << 3)];
      }
#pragma unroll
      for (int ni = 0; ni < 4; ++ni) {
        int row = wc * 64 + ni * 16 + lr;
        b[ni] = *(const short8*)&embT[row * 256 + (((ks * 4 + lk) ^ (row & 7)) << 3)];
      }
#pragma unroll
      for (int mi = 0; mi < 4; ++mi)
#pragma unroll
        for (int ni = 0; ni < 4; ++ni)
          acc[mi][ni] = __builtin_amdgcn_mfma_f32_16x16x32_bf16(a[mi], b[ni], acc[mi][ni], 0, 0, 0);
    }

    if (MODE == 0) {
#pragma unroll
      for (int mi = 0; mi < 4; ++mi) {
        float part[4];
#pragma unroll
        for (int r = 0; r < 4; ++r) {
          float p = 0.f;
#pragma unroll
          for (int ni = 0; ni < 4; ++ni) {
            int v = v0 + wc * 64 + ni * 16 + (lane & 15);
            float e = __expf(acc[mi][ni][r]);
            p += (v < VOCAB) ? e : 0.f;
          }
#pragma unroll
          for (int off = 1; off < 16; off <<= 1) p += __shfl_xor(p, off, 64);
          part[r] = p;
        }
        if ((lane & 15) == 0) {
          int m = mt * 128 + wr * 64 + mi * 16 + (lane >> 4) * 4;
#pragma unroll
          for (int r = 0; r < 4; ++r) atomicAdd(&s[m + r], part[r]);
        }
      }
    } else {
#pragma unroll
      for (int mi = 0; mi < 4; ++mi) {
        int m = mt * 128 + wr * 64 + mi * 16 + (lane >> 4) * 4;  // multiple of 4
        float4 wv = *(const float4*)&w[m];
#pragma unroll
        for (int ni = 0; ni < 4; ++ni) {
          int v = v0 + wc * 64 + ni * 16 + (lane & 15);
          if (v < VOCAB) {
            float val = wv.x * __expf(acc[mi][ni][0]) + wv.y * __expf(acc[mi][ni][1]) +
                        wv.z * __expf(acc[mi][ni][2]) + wv.w * __expf(acc[mi][ni][3]);
            out[(size_t)(m >> 2) * VOCAB + v] = val;
          }
        }
      }
    }
  }
}

// ---------------- kernel 4: w = pi / s ------------------------------------------
__global__ void wk_kernel(const float* __restrict__ pi, const float* __restrict__ s,
                          float* __restrict__ w) {
  int m = blockIdx.x * 256 + threadIdx.x;
  if (m < 4096) w[m] = pi[m] / s[m];
}

extern "C" void kernel_launch(void* const* d_in, const int* in_sizes, int n_in,
                              void* d_out, int out_size, void* d_ws, size_t ws_size,
                              hipStream_t stream) {
  const float* x        = (const float*)d_in[0];
  const float* proj_mat = (const float*)d_in[1];
  const float* mix_mat  = (const float*)d_in[2];
  const float* emb      = (const float*)d_in[3];
  float* out = (float*)d_out;

  char* ws = (char*)d_ws;
  short* projA = (short*)ws;                    // bf16 [4096][256] = 2 MB
  float* pi    = (float*)(ws + 2097152);        // [4096]
  float* s     = (float*)(ws + 2113536);        // [4096]
  float* w     = (float*)(ws + 2129920);        // [4096]

  hipMemsetAsync(s, 0, 16384, stream);

  dim3 g1(16, 16);
  proj_kernel<<<g1, 256, 0, stream>>>(x, proj_mat, projA);
  pi_kernel<<<4, 256, 0, stream>>>(x, mix_mat, pi);

  const int nblk = (VOCAB + 127) / 128;  // 782
  mos_gemm<0><<<nblk, 256, 0, stream>>>(emb, projA, nullptr, s, nullptr);
  wk_kernel<<<16, 256, 0, stream>>>(pi, s, w);
  mos_gemm<1><<<nblk, 256, 0, stream>>>(emb, projA, w, nullptr, out);
}

// Round 2
// 1288.810 us; speedup vs baseline: 1.3619x; 1.3619x over previous
//
#include <hip/hip_runtime.h>
#include <stdint.h>

// MixtureOfSoftmaxes: B=1024, H=4, D=256, V=100000
// out[b,v] = sum_h pi[b,h] * softmax_v(proj[b,h,:]·emb[v,:])
// No-max softmax (|logits| < ~3):
//   pass C: s[m] = sum_v exp(l[m,v])   (m = b*4+h)
//   pass D: out[b,v] = sum_h (pi/s)[m] * exp(l[m,v])

#define VOCAB 100000

typedef __attribute__((ext_vector_type(8))) short short8;
typedef __attribute__((ext_vector_type(4))) float f32x4;

__device__ __forceinline__ short f2bf(float f) {
  uint32_t u = __float_as_uint(f);
  u = (u + 0x7FFFu + ((u >> 16) & 1u)) >> 16;
  return (short)u;
}

// ---------------- kernel 1: proj = tanh(x @ proj_mat^T) -> bf16 [4096 x 256] ----
__global__ __launch_bounds__(256) void proj_kernel(const float* __restrict__ x,
                                                   const float* __restrict__ pm,
                                                   short* __restrict__ projA) {
  __shared__ float xs[64][36];
  __shared__ float ps[64][36];
  const int tid = threadIdx.x;
  const int tx = tid & 15, ty = tid >> 4;
  const int m0 = blockIdx.y * 64, n0 = blockIdx.x * 64;
  float acc[4][4];
#pragma unroll
  for (int i = 0; i < 4; i++)
#pragma unroll
    for (int j = 0; j < 4; j++) acc[i][j] = 0.f;

  for (int k0 = 0; k0 < 256; k0 += 32) {
    const int r = tid >> 2, c = (tid & 3) * 8;
    *(float4*)&xs[r][c]     = *(const float4*)&x[(m0 + r) * 256 + k0 + c];
    *(float4*)&xs[r][c + 4] = *(const float4*)&x[(m0 + r) * 256 + k0 + c + 4];
    *(float4*)&ps[r][c]     = *(const float4*)&pm[(n0 + r) * 256 + k0 + c];
    *(float4*)&ps[r][c + 4] = *(const float4*)&pm[(n0 + r) * 256 + k0 + c + 4];
    __syncthreads();
#pragma unroll
    for (int kk = 0; kk < 32; kk += 4) {
      float4 xa[4], pb[4];
#pragma unroll
      for (int i = 0; i < 4; i++) xa[i] = *(const float4*)&xs[ty * 4 + i][kk];
#pragma unroll
      for (int j = 0; j < 4; j++) pb[j] = *(const float4*)&ps[tx * 4 + j][kk];
#pragma unroll
      for (int i = 0; i < 4; i++)
#pragma unroll
        for (int j = 0; j < 4; j++)
          acc[i][j] += xa[i].x * pb[j].x + xa[i].y * pb[j].y +
                       xa[i].z * pb[j].z + xa[i].w * pb[j].w;
    }
    __syncthreads();
  }
#pragma unroll
  for (int i = 0; i < 4; i++)
#pragma unroll
    for (int j = 0; j < 4; j++)
      projA[(size_t)(m0 + ty * 4 + i) * 1024 + (n0 + tx * 4 + j)] = f2bf(tanhf(acc[i][j]));
}

// ---------------- kernel 2: pi = softmax(x @ mix_mat^T)  [1024 x 4] --------------
__global__ __launch_bounds__(256) void pi_kernel(const float* __restrict__ x,
                                                 const float* __restrict__ mm,
                                                 float* __restrict__ pi) {
  int b = blockIdx.x * 256 + threadIdx.x;
  if (b >= 1024) return;
  float acc[4] = {0.f, 0.f, 0.f, 0.f};
  for (int k = 0; k < 256; k += 4) {
    float4 xv = *(const float4*)&x[(size_t)b * 256 + k];
#pragma unroll
    for (int h = 0; h < 4; h++) {
      float4 mv = *(const float4*)&mm[h * 256 + k];
      acc[h] += xv.x * mv.x + xv.y * mv.y + xv.z * mv.z + xv.w * mv.w;
    }
  }
  float mx = fmaxf(fmaxf(acc[0], acc[1]), fmaxf(acc[2], acc[3]));
  float e[4], ssum = 0.f;
#pragma unroll
  for (int h = 0; h < 4; h++) { e[h] = __expf(acc[h] - mx); ssum += e[h]; }
#pragma unroll
  for (int h = 0; h < 4; h++) pi[b * 4 + h] = e[h] / ssum;
}

// ---------------- big GEMM: A staged in LDS (K-halves, pipelined), B in regs ----
// Block: 128 v-cols × (loop over 32 m-tiles of 128 rows). 4 waves: wr=m-half, wc=v-half.
// Wave tile: 64m × 64v  (mi=4, ni=4), B frags held in regs for the full K=256.

__device__ __forceinline__ void stage_half(const short* __restrict__ projA, int mt, int h,
                                           short* buf, int tid, int wid) {
#pragma unroll
  for (int j = 0; j < 8; ++j) {
    int g = j * 256 + tid;       // 16B chunk index in half-buffer (2048 chunks)
    int r = g >> 4;              // m row 0..127
    int c = g & 15;              // 16B chunk within 256B half-row
    const char* src = (const char*)projA +
                      ((size_t)(mt * 128 + r) * 512 + h * 256 + ((c ^ (r & 15)) << 4));
    char* dst = (char*)buf + (j * 4096 + wid * 1024);  // wave-uniform base
    __builtin_amdgcn_global_load_lds((const __attribute__((address_space(1))) void*)src,
                                     (__attribute__((address_space(3))) void*)dst,
                                     16, 0, 0);
  }
}

template <int KOFF>
__device__ __forceinline__ void compute_half(const short* __restrict__ buf,
                                             const short8 (&Bf)[4][8], f32x4 (&acc)[4][4],
                                             int wr, int l15, int l4) {
#pragma unroll
  for (int ks = 0; ks < 4; ++ks) {
    short8 a[4];
#pragma unroll
    for (int mi = 0; mi < 4; ++mi) {
      int row = wr * 64 + mi * 16 + l15;
      int chunk = (ks * 4 + l4) ^ l15;       // row&15 == l15
      a[mi] = *(const short8*)&buf[row * 128 + chunk * 8];
    }
#pragma unroll
    for (int mi = 0; mi < 4; ++mi)
#pragma unroll
      for (int ni = 0; ni < 4; ++ni)
        acc[mi][ni] =
            __builtin_amdgcn_mfma_f32_16x16x32_bf16(a[mi], Bf[ni][KOFF + ks], acc[mi][ni], 0, 0, 0);
  }
}

template <int MODE>
__global__ __launch_bounds__(256, 2) void mos_gemm(const float* __restrict__ emb,
                                                   const short* __restrict__ projA,
                                                   const float* __restrict__ w,
                                                   float* __restrict__ s,
                                                   float* __restrict__ out) {
  __shared__ short At[2][128 * 128];  // 2 x 32 KB K-half buffers
  const int tid = threadIdx.x;
  const int lane = tid & 63, wid = tid >> 6;
  const int wr = wid >> 1, wc = wid & 1;
  const int l15 = lane & 15, l4 = lane >> 4;
  const int v0 = blockIdx.x * 128;

  // ---- prologue: B (emb) fragments for full K into registers, fp32 -> bf16 ----
  short8 Bf[4][8];  // [ni][ks]  128 VGPR
#pragma unroll
  for (int ni = 0; ni < 4; ++ni) {
    int v = v0 + wc * 64 + ni * 16 + l15;
    v = (v < VOCAB) ? v : (VOCAB - 1);
    const float* src = emb + (size_t)v * 256 + l4 * 8;
#pragma unroll
    for (int ks = 0; ks < 8; ++ks) {
      float4 f0 = *(const float4*)(src + ks * 32);
      float4 f1 = *(const float4*)(src + ks * 32 + 4);
      short8 b8;
      b8[0] = f2bf(f0.x); b8[1] = f2bf(f0.y); b8[2] = f2bf(f0.z); b8[3] = f2bf(f0.w);
      b8[4] = f2bf(f1.x); b8[5] = f2bf(f1.y); b8[6] = f2bf(f1.z); b8[7] = f2bf(f1.w);
      Bf[ni][ks] = b8;
    }
  }

  f32x4 acc[4][4];
#pragma unroll
  for (int mi = 0; mi < 4; ++mi)
#pragma unroll
    for (int ni = 0; ni < 4; ++ni) acc[mi][ni] = (f32x4){0.f, 0.f, 0.f, 0.f};

  stage_half(projA, 0, 0, At[0], tid, wid);
  __syncthreads();  // drains vmcnt -> At[0] ready

#pragma unroll 1
  for (int mt = 0; mt < 32; ++mt) {
    // half 0: prefetch K-half 1, compute K-half 0
    stage_half(projA, mt, 1, At[1], tid, wid);
    compute_half<0>(At[0], Bf, acc, wr, l15, l4);
    __syncthreads();  // At[1] ready; everyone done reading At[0]

    // half 1: prefetch next tile's K-half 0, compute K-half 1
    if (mt < 31) stage_half(projA, mt + 1, 0, At[0], tid, wid);
    compute_half<4>(At[1], Bf, acc, wr, l15, l4);

    // ---- epilogue for this m-tile ----
    if (MODE == 0) {
#pragma unroll
      for (int mi = 0; mi < 4; ++mi) {
        float pr[4];
#pragma unroll
        for (int r = 0; r < 4; ++r) {
          float p = 0.f;
#pragma unroll
          for (int ni = 0; ni < 4; ++ni) {
            int v = v0 + wc * 64 + ni * 16 + l15;
            float e = __expf(acc[mi][ni][r]);
            p += (v < VOCAB) ? e : 0.f;
          }
          p += __shfl_xor(p, 1, 64);
          p += __shfl_xor(p, 2, 64);
          p += __shfl_xor(p, 4, 64);
          p += __shfl_xor(p, 8, 64);
          pr[r] = p;
        }
        if (l15 == 0) {
          int m = mt * 128 + wr * 64 + mi * 16 + l4 * 4;
#pragma unroll
          for (int r = 0; r < 4; ++r) atomicAdd(&s[m + r], pr[r]);
        }
      }
    } else {
#pragma unroll
      for (int mi = 0; mi < 4; ++mi) {
        int m = mt * 128 + wr * 64 + mi * 16 + l4 * 4;  // multiple of 4
        float4 wv = *(const float4*)&w[m];
#pragma unroll
        for (int ni = 0; ni < 4; ++ni) {
          int v = v0 + wc * 64 + ni * 16 + l15;
          if (v < VOCAB) {
            out[(size_t)(m >> 2) * VOCAB + v] =
                wv.x * __expf(acc[mi][ni][0]) + wv.y * __expf(acc[mi][ni][1]) +
                wv.z * __expf(acc[mi][ni][2]) + wv.w * __expf(acc[mi][ni][3]);
          }
        }
      }
    }
#pragma unroll
    for (int mi = 0; mi < 4; ++mi)
#pragma unroll
      for (int ni = 0; ni < 4; ++ni) acc[mi][ni] = (f32x4){0.f, 0.f, 0.f, 0.f};

    __syncthreads();  // At[0] restaged for next mt; everyone done with At[1]
  }
}

// ---------------- kernel 4: w = pi / s ------------------------------------------
__global__ void wk_kernel(const float* __restrict__ pi, const float* __restrict__ s,
                          float* __restrict__ w) {
  int m = blockIdx.x * 256 + threadIdx.x;
  if (m < 4096) w[m] = pi[m] / s[m];
}

extern "C" void kernel_launch(void* const* d_in, const int* in_sizes, int n_in,
                              void* d_out, int out_size, void* d_ws, size_t ws_size,
                              hipStream_t stream) {
  const float* x        = (const float*)d_in[0];
  const float* proj_mat = (const float*)d_in[1];
  const float* mix_mat  = (const float*)d_in[2];
  const float* emb      = (const float*)d_in[3];
  float* out = (float*)d_out;

  char* ws = (char*)d_ws;
  short* projA = (short*)ws;                    // bf16 [4096][256] = 2 MB
  float* pi    = (float*)(ws + 2097152);        // [4096]
  float* s     = (float*)(ws + 2113536);        // [4096]
  float* w     = (float*)(ws + 2129920);        // [4096]

  hipMemsetAsync(s, 0, 16384, stream);

  dim3 g1(16, 16);
  proj_kernel<<<g1, 256, 0, stream>>>(x, proj_mat, projA);
  pi_kernel<<<4, 256, 0, stream>>>(x, mix_mat, pi);

  const int nblk = (VOCAB + 127) / 128;  // 782
  mos_gemm<0><<<nblk, 256, 0, stream>>>(emb, projA, nullptr, s, nullptr);
  wk_kernel<<<16, 256, 0, stream>>>(pi, s, w);
  mos_gemm<1><<<nblk, 256, 0, stream>>>(emb, projA, w, nullptr, out);
}

// Round 3
// 792.407 us; speedup vs baseline: 2.2151x; 1.6264x over previous
//
#include <hip/hip_runtime.h>
#include <stdint.h>

// MixtureOfSoftmaxes: B=1024, H=4, D=256, V=100000
// out[b,v] = sum_h pi[b,h] * softmax_v(proj[b,h,:]·emb[v,:])
// No-max softmax (|logits| < ~3):
//   pass C: part[blk][m] = sum_{v in blk} exp(l[m,v]);  reduce -> s[m];  w = pi/s
//   pass D: out[b,v] = sum_h w[m]*exp(l[m,v])
// GEMM: 512-thr blocks, 4x32KB LDS slots (A=projA staged 2 phases ahead via
// global_load_lds), emb frags register-resident, raw s_barrier + counted vmcnt.

#define VOCAB 100000
#define NBLK 782

typedef __attribute__((ext_vector_type(8))) short short8;
typedef __attribute__((ext_vector_type(4))) float f32x4;

__device__ __forceinline__ short f2bf(float f) {
  uint32_t u = __float_as_uint(f);
  u = (u + 0x7FFFu + ((u >> 16) & 1u)) >> 16;
  return (short)u;
}

#define VMCNT(n) asm volatile("s_waitcnt vmcnt(" #n ")" ::: "memory")
#define LGKM0() asm volatile("s_waitcnt lgkmcnt(0)" ::: "memory")
#define SCHED0() __builtin_amdgcn_sched_barrier(0)
#define BAR() __builtin_amdgcn_s_barrier()

// ---------------- kernel 1: proj = tanh(x @ proj_mat^T) -> bf16 [4096 x 256] ----
__global__ __launch_bounds__(256) void proj_kernel(const float* __restrict__ x,
                                                   const float* __restrict__ pm,
                                                   short* __restrict__ projA) {
  __shared__ float xs[64][36];
  __shared__ float ps[64][36];
  const int tid = threadIdx.x;
  const int tx = tid & 15, ty = tid >> 4;
  const int m0 = blockIdx.y * 64, n0 = blockIdx.x * 64;
  float acc[4][4];
#pragma unroll
  for (int i = 0; i < 4; i++)
#pragma unroll
    for (int j = 0; j < 4; j++) acc[i][j] = 0.f;

  for (int k0 = 0; k0 < 256; k0 += 32) {
    const int r = tid >> 2, c = (tid & 3) * 8;
    *(float4*)&xs[r][c]     = *(const float4*)&x[(m0 + r) * 256 + k0 + c];
    *(float4*)&xs[r][c + 4] = *(const float4*)&x[(m0 + r) * 256 + k0 + c + 4];
    *(float4*)&ps[r][c]     = *(const float4*)&pm[(n0 + r) * 256 + k0 + c];
    *(float4*)&ps[r][c + 4] = *(const float4*)&pm[(n0 + r) * 256 + k0 + c + 4];
    __syncthreads();
#pragma unroll
    for (int kk = 0; kk < 32; kk += 4) {
      float4 xa[4], pb[4];
#pragma unroll
      for (int i = 0; i < 4; i++) xa[i] = *(const float4*)&xs[ty * 4 + i][kk];
#pragma unroll
      for (int j = 0; j < 4; j++) pb[j] = *(const float4*)&ps[tx * 4 + j][kk];
#pragma unroll
      for (int i = 0; i < 4; i++)
#pragma unroll
        for (int j = 0; j < 4; j++)
          acc[i][j] += xa[i].x * pb[j].x + xa[i].y * pb[j].y +
                       xa[i].z * pb[j].z + xa[i].w * pb[j].w;
    }
    __syncthreads();
  }
#pragma unroll
  for (int i = 0; i < 4; i++)
#pragma unroll
    for (int j = 0; j < 4; j++)
      projA[(size_t)(m0 + ty * 4 + i) * 1024 + (n0 + tx * 4 + j)] = f2bf(tanhf(acc[i][j]));
}

// ---------------- kernel 2: pi = softmax(x @ mix_mat^T)  [1024 x 4] --------------
__global__ __launch_bounds__(256) void pi_kernel(const float* __restrict__ x,
                                                 const float* __restrict__ mm,
                                                 float* __restrict__ pi) {
  int b = blockIdx.x * 256 + threadIdx.x;
  if (b >= 1024) return;
  float acc[4] = {0.f, 0.f, 0.f, 0.f};
  for (int k = 0; k < 256; k += 4) {
    float4 xv = *(const float4*)&x[(size_t)b * 256 + k];
#pragma unroll
    for (int h = 0; h < 4; h++) {
      float4 mv = *(const float4*)&mm[h * 256 + k];
      acc[h] += xv.x * mv.x + xv.y * mv.y + xv.z * mv.z + xv.w * mv.w;
    }
  }
  float mx = fmaxf(fmaxf(acc[0], acc[1]), fmaxf(acc[2], acc[3]));
  float e[4], ssum = 0.f;
#pragma unroll
  for (int h = 0; h < 4; h++) { e[h] = __expf(acc[h] - mx); ssum += e[h]; }
#pragma unroll
  for (int h = 0; h < 4; h++) pi[b * 4 + h] = e[h] / ssum;
}

// ---------------- big GEMM ------------------------------------------------------
// stage one 32KB half-tile (128 m-rows x 128 k-cols bf16), XOR-swizzled source.
__device__ __forceinline__ void stage(const short* __restrict__ projA, int mt, int h,
                                      short* buf, int tid, int wid) {
#pragma unroll
  for (int j = 0; j < 4; ++j) {
    int g = j * 512 + tid;   // 16B chunk 0..2047
    int r = g >> 4, c = g & 15;
    const char* src = (const char*)projA +
                      ((size_t)(mt * 128 + r) * 512 + h * 256 + ((c ^ (r & 15)) << 4));
    char* dst = (char*)buf + (j * 8192 + wid * 1024);  // wave-uniform base
    __builtin_amdgcn_global_load_lds((const __attribute__((address_space(1))) void*)src,
                                     (__attribute__((address_space(3))) void*)dst, 16, 0, 0);
  }
}

template <int KOFF>
__device__ __forceinline__ void compute_phase(const short* buf, const short8 (&Bf)[4][8],
                                              f32x4 (&acc)[2][4], int mq, int l15, int l4) {
#pragma unroll
  for (int ks = 0; ks < 4; ++ks) {
    short8 a[2];
#pragma unroll
    for (int mi = 0; mi < 2; ++mi) {
      int row = mq * 32 + mi * 16 + l15;
      int chunk = (ks * 4 + l4) ^ l15;  // row&15 == l15
      a[mi] = *(const short8*)&buf[row * 128 + chunk * 8];
    }
    __builtin_amdgcn_s_setprio(1);
#pragma unroll
    for (int mi = 0; mi < 2; ++mi)
#pragma unroll
      for (int ni = 0; ni < 4; ++ni)
        acc[mi][ni] =
            __builtin_amdgcn_mfma_f32_16x16x32_bf16(a[mi], Bf[ni][KOFF + ks], acc[mi][ni], 0, 0, 0);
    __builtin_amdgcn_s_setprio(0);
  }
}

// epilogue per tile: 8 global stores per wave in BOTH modes (uniform vmcnt counts)
template <int MODE>
__device__ __forceinline__ void epilogue(f32x4 (&acc)[2][4], int t, int v0, int mq, int vh,
                                         int l15, int l4, int lane, const float* __restrict__ w,
                                         float* __restrict__ part, float* __restrict__ dump,
                                         float* __restrict__ out, float* red, int bid) {
  if (MODE == 0) {
    float p[2][4];
#pragma unroll
    for (int mi = 0; mi < 2; ++mi)
#pragma unroll
      for (int r = 0; r < 4; ++r) {
        float s = 0.f;
#pragma unroll
        for (int ni = 0; ni < 4; ++ni) {
          int v = v0 + vh * 64 + ni * 16 + l15;
          float e = __expf(acc[mi][ni][r]);
          s += (v < VOCAB) ? e : 0.f;
        }
        s += __shfl_xor(s, 1, 64);
        s += __shfl_xor(s, 2, 64);
        s += __shfl_xor(s, 4, 64);
        s += __shfl_xor(s, 8, 64);
        p[mi][r] = s;
      }
    if (vh == 0) {
      if (l15 == 0) {
#pragma unroll
        for (int mi = 0; mi < 2; ++mi)
#pragma unroll
          for (int r = 0; r < 4; ++r) red[mq * 32 + mi * 16 + l4 * 4 + r] = p[mi][r];
      }
    }
    LGKM0();
    BAR();
    SCHED0();
    if (vh == 1) {
      if (l15 == 0) {
#pragma unroll
        for (int mi = 0; mi < 2; ++mi)
#pragma unroll
          for (int r = 0; r < 4; ++r) {
            int rloc = mq * 32 + mi * 16 + l4 * 4 + r;
            part[(size_t)bid * 4096 + t * 128 + rloc] = p[mi][r] + red[rloc];
          }
      }
    } else {
      if (l15 == 0) {
#pragma unroll
        for (int mi = 0; mi < 2; ++mi)
#pragma unroll
          for (int r = 0; r < 4; ++r) {
            int rloc = mq * 32 + mi * 16 + l4 * 4 + r;
            dump[t * 128 + rloc] = p[mi][r];  // junk, equalizes store counts
          }
      }
    }
  } else {
#pragma unroll
    for (int mi = 0; mi < 2; ++mi) {
      int m = t * 128 + mq * 32 + mi * 16 + l4 * 4;
      float4 wv = *(const float4*)&w[m];
#pragma unroll
      for (int ni = 0; ni < 4; ++ni) {
        int v = v0 + vh * 64 + ni * 16 + l15;
        float val = wv.x * __expf(acc[mi][ni][0]) + wv.y * __expf(acc[mi][ni][1]) +
                    wv.z * __expf(acc[mi][ni][2]) + wv.w * __expf(acc[mi][ni][3]);
        float* tgt = (v < VOCAB) ? (out + (size_t)(m >> 2) * VOCAB + v) : (dump + lane);
        *tgt = val;  // unconditional issue: uniform vmcnt counts
      }
    }
  }
#pragma unroll
  for (int mi = 0; mi < 2; ++mi)
#pragma unroll
    for (int ni = 0; ni < 4; ++ni) acc[mi][ni] = (f32x4){0.f, 0.f, 0.f, 0.f};
}

template <int MODE>
__global__ __launch_bounds__(512, 2) void mos_gemm(const float* __restrict__ emb,
                                                   const short* __restrict__ projA,
                                                   const float* __restrict__ w,
                                                   float* __restrict__ part,
                                                   float* __restrict__ dump,
                                                   float* __restrict__ out) {
  __shared__ short S0[128 * 128], S1[128 * 128], S2[128 * 128], S3[128 * 128];
  __shared__ float red[128];
  const int tid = threadIdx.x;
  const int lane = tid & 63, wid = tid >> 6;
  const int mq = wid & 3, vh = wid >> 2;
  const int l15 = lane & 15, l4 = lane >> 4;
  const int v0 = blockIdx.x * 128;
  const int bid = blockIdx.x;

  // ---- prologue: emb fragments for full K=256 into registers (fp32 -> bf16) ----
  short8 Bf[4][8];
#pragma unroll
  for (int ni = 0; ni < 4; ++ni) {
    int v = v0 + vh * 64 + ni * 16 + l15;
    v = (v < VOCAB) ? v : (VOCAB - 1);
    const float* src = emb + (size_t)v * 256 + l4 * 8;
#pragma unroll
    for (int ks = 0; ks < 8; ++ks) {
      float4 f0 = *(const float4*)(src + ks * 32);
      float4 f1 = *(const float4*)(src + ks * 32 + 4);
      short8 b8;
      b8[0] = f2bf(f0.x); b8[1] = f2bf(f0.y); b8[2] = f2bf(f0.z); b8[3] = f2bf(f0.w);
      b8[4] = f2bf(f1.x); b8[5] = f2bf(f1.y); b8[6] = f2bf(f1.z); b8[7] = f2bf(f1.w);
      Bf[ni][ks] = b8;
    }
  }
  SCHED0();

  f32x4 acc[2][4];
#pragma unroll
  for (int mi = 0; mi < 2; ++mi)
#pragma unroll
    for (int ni = 0; ni < 4; ++ni) acc[mi][ni] = (f32x4){0.f, 0.f, 0.f, 0.f};

  // prologue stages: L(0,0)->S0, L(0,1)->S1, L(1,0)->S2   (3 half-tiles deep)
  stage(projA, 0, 0, S0, tid, wid);
  stage(projA, 0, 1, S1, tid, wid);
  stage(projA, 1, 0, S2, tid, wid);
  SCHED0();
  VMCNT(8);  // L(0,0) landed
  BAR();
  SCHED0();

#pragma unroll 1
  for (int tt = 0; tt < 16; ++tt) {
    const int t0 = tt * 2, t1 = tt * 2 + 1;
    // ---- phase A: tile t0 half 0 (S0); stage L(t0+1,1)->S3 ----
    stage(projA, t1, 1, S3, tid, wid);
    SCHED0();
    compute_phase<0>(S0, Bf, acc, mq, l15, l4);
    LGKM0();
    if (tt == 0) { VMCNT(8); } else { VMCNT(12); }
    BAR();
    SCHED0();

    // ---- phase B: tile t0 half 1 (S1); stage L(t0+2,0)->S0; epilogue t0 ----
    if (tt < 15) stage(projA, t0 + 2, 0, S0, tid, wid);
    SCHED0();
    compute_phase<4>(S1, Bf, acc, mq, l15, l4);
    epilogue<MODE>(acc, t0, v0, mq, vh, l15, l4, lane, w, part, dump, out, red, bid);
    LGKM0();
    VMCNT(12);
    BAR();
    SCHED0();

    // ---- phase C: tile t1 half 0 (S2); stage L(t1+1,1)->S1 ----
    if (tt < 15) stage(projA, t1 + 1, 1, S1, tid, wid);
    SCHED0();
    compute_phase<0>(S2, Bf, acc, mq, l15, l4);
    LGKM0();
    if (tt == 15) { VMCNT(8); } else { VMCNT(12); }
    BAR();
    SCHED0();

    // ---- phase D: tile t1 half 1 (S3); stage L(t1+2,0)->S2; epilogue t1 ----
    if (tt < 15) stage(projA, t1 + 2, 0, S2, tid, wid);
    SCHED0();
    compute_phase<4>(S3, Bf, acc, mq, l15, l4);
    epilogue<MODE>(acc, t1, v0, mq, vh, l15, l4, lane, w, part, dump, out, red, bid);
    LGKM0();
    VMCNT(12);
    BAR();
    SCHED0();
  }
}

// ---------------- reduce partials + w = pi / s ----------------------------------
__global__ __launch_bounds__(256) void reduce_w(const float* __restrict__ part,
                                                const float* __restrict__ pi,
                                                float* __restrict__ w) {
  int m = blockIdx.x * 256 + threadIdx.x;  // 0..4095
  float sum = 0.f;
  for (int b = 0; b < NBLK; ++b) sum += part[(size_t)b * 4096 + m];
  w[m] = pi[m] / sum;
}

extern "C" void kernel_launch(void* const* d_in, const int* in_sizes, int n_in,
                              void* d_out, int out_size, void* d_ws, size_t ws_size,
                              hipStream_t stream) {
  const float* x        = (const float*)d_in[0];
  const float* proj_mat = (const float*)d_in[1];
  const float* mix_mat  = (const float*)d_in[2];
  const float* emb      = (const float*)d_in[3];
  float* out = (float*)d_out;

  char* ws = (char*)d_ws;
  short* projA = (short*)ws;                        // bf16 [4096][256] = 2 MB
  float* pi    = (float*)(ws + (2u << 20));         // [4096]
  float* w     = (float*)(ws + (2u << 20) + 16384); // [4096]
  float* part  = (float*)(ws + (2u << 20) + 32768); // [NBLK][4096] = 12.8 MB
  float* dump  = part + (size_t)NBLK * 4096;        // 16 KB junk sink

  dim3 g1(16, 16);
  proj_kernel<<<g1, 256, 0, stream>>>(x, proj_mat, projA);
  pi_kernel<<<4, 256, 0, stream>>>(x, mix_mat, pi);

  mos_gemm<0><<<NBLK, 512, 0, stream>>>(emb, projA, nullptr, part, dump, nullptr);
  reduce_w<<<16, 256, 0, stream>>>(part, pi, w);
  mos_gemm<1><<<NBLK, 512, 0, stream>>>(emb, projA, w, nullptr, dump, out);
}